// Round 13
// baseline (165.025 us; speedup 1.0000x reference)
//
#include <hip/hip_runtime.h>
#include <hip/hip_bf16.h>

// TreeCNN on MI355X — bf16 MFMA, split-kernel structure (serial BN chain).
// R13: G1A ts0 via shfl+LDS block-reduction (16x fewer atomics); first B-stage
// issued before the pooling read (async overlap).
// 9 dispatches: memset, transpose, G1A, G1B, G2A(pool8+ts1), G2B, G3A(pool32), G3B, head.

#define N0 (256*2048)
#define N1 (256*256)
#define N2 (256*32)
#define NB 256
#define BN_EPS 1e-5f
#define NSLOT 8

typedef __attribute__((ext_vector_type(8))) __bf16 bf16x8;
typedef __attribute__((ext_vector_type(8))) unsigned short u16x8;
typedef __attribute__((ext_vector_type(4))) unsigned short u16x4;
typedef __attribute__((ext_vector_type(4))) float f32x4;

__device__ inline float bf2f(unsigned short b) {
    unsigned u = ((unsigned)b) << 16;
    float f; __builtin_memcpy(&f, &u, 4); return f;
}
__device__ inline unsigned short f2bf(float f) {
    unsigned u; __builtin_memcpy(&u, &f, 4);
    u += 0x7fff + ((u >> 16) & 1);
    return (unsigned short)(u >> 16);
}

// 16B async global->LDS. LDS dest is wave-uniform base + lane*16 (linear!).
__device__ __forceinline__ void gload_lds16(const void* g, void* l) {
    __builtin_amdgcn_global_load_lds((const __attribute__((address_space(1))) unsigned int*)g,
                                     (__attribute__((address_space(3))) unsigned int*)l,
                                     16, 0, 0);
}

// Stage B-tile [256 rows][64 k-shorts] from Wt(+ktile) with XOR-swizzle:
// LDS[n][p] = B[n][p ^ (n&7)] (granule = 16B). 512 threads, 8 waves, 4 iters.
__device__ __forceinline__ void stage_B_swz(const unsigned short* __restrict__ Wsrc,
                                            int K, unsigned short* Bsb) {
    const int wave = threadIdx.x >> 6, lane = threadIdx.x & 63;
#pragma unroll
    for (int i = 0; i < 4; ++i) {
        int gbase = (wave * 4 + i) * 64;     // wave-uniform granule base
        int idx = gbase + lane;              // this lane's granule
        int n = idx >> 3, p = idx & 7;
        gload_lds16(Wsrc + (size_t)n * K + ((p ^ (n & 7)) << 3), &Bsb[gbase * 8]);
    }
}

// Swizzled B read: logical granule g = s*4+q, physical = g ^ (r&7). Row stride 64 shorts.
#define BSWZ(row, s, q, r) (((row) * 64) + ((((s) * 4 + (q)) ^ ((r) & 7)) << 3))

// ---------- weights: LDS-tiled transpose + f32->bf16, Wt[n][k] ----------
__global__ __launch_bounds__(256) void transpose_weights(const float* __restrict__ l1_w1,
                                                         const float* __restrict__ l1_w2,
                                                         const float* __restrict__ lw1,
                                                         const float* __restrict__ lw2,
                                                         unsigned short* __restrict__ Wt) {
    __shared__ float t[32][33];
    const int bid = blockIdx.x;
    const float* src; unsigned short* dst; int K, tile;
    if (bid < 32)        { src = l1_w1;         dst = Wt;          K = 128; tile = bid; }
    else if (bid < 96)   { src = l1_w2;         dst = Wt + 32768;  K = 256; tile = bid - 32; }
    else if (bid < 160)  { src = lw1;           dst = Wt + 98304;  K = 256; tile = bid - 96; }
    else if (bid < 224)  { src = lw2;           dst = Wt + 163840; K = 256; tile = bid - 160; }
    else if (bid < 288)  { src = lw1 + 65536;   dst = Wt + 229376; K = 256; tile = bid - 224; }
    else                 { src = lw2 + 65536;   dst = Wt + 294912; K = 256; tile = bid - 288; }
    const int ti = tile >> 3, tj = tile & 7;   // k-tile, n-tile
    const int lx = threadIdx.x & 31, ly = threadIdx.x >> 5;
#pragma unroll
    for (int i = 0; i < 4; ++i) {
        int k = ti * 32 + ly + i * 8;
        t[ly + i * 8][lx] = src[(size_t)k * 256 + tj * 32 + lx];
    }
    __syncthreads();
#pragma unroll
    for (int i = 0; i < 4; ++i) {
        int n = tj * 32 + ly + i * 8;
        dst[(size_t)n * K + ti * 32 + lx] = f2bf(t[lx][ly + i * 8]);
    }
}

// ---------- BN finalize prologue (8-slot partials -> scale/shift in LDS) ----------
__device__ __forceinline__ void bn_prologue(int tid, const float* __restrict__ partials,
                                            const float* __restrict__ g, const float* __restrict__ b,
                                            float invM, float* sc_lds, float* sh_lds) {
    if (tid < 256) {
        float s = 0.f, s2 = 0.f;
#pragma unroll
        for (int k = 0; k < NSLOT; ++k) {
            s  += partials[k * 512 + tid];
            s2 += partials[k * 512 + 256 + tid];
        }
        float mean = s * invM;
        float var = s2 * invM - mean * mean;
        float sc = g[tid] * rsqrtf(var + BN_EPS);
        sc_lds[tid] = sc;
        sh_lds[tid] = b[tid] - mean * sc;
    }
}

// ---------- G1A: x -> pool8(f32) -> A-tile @ W1 -> Z1; fused ts0 + stats ----------
__global__ __launch_bounds__(512, 4) void gemm1_fused(const float* __restrict__ x,
                                                      const unsigned short* __restrict__ Wt,
                                                      const float* __restrict__ bias,
                                                      unsigned short* __restrict__ Z1,
                                                      float* __restrict__ stat_partials,
                                                      float* __restrict__ ts0) {
    constexpr int LDA = 136;
    __shared__ unsigned short Asb[128 * LDA];
    __shared__ unsigned short Bsb[256 * 64];
    __shared__ float red0[8][32][4];         // per-wave ts0 partials
    const int tid = threadIdx.x;
    const int c4 = tid & 31, rg = tid >> 5;
    const int m0 = blockIdx.x * 128;
    const int tree = blockIdx.x >> 1;
    const int wave = tid >> 6, lane = tid & 63;

    stage_B_swz(Wt, 128, Bsb);               // async: flies under the pooling read

    f32x4 colp = {0.f, 0.f, 0.f, 0.f};
#pragma unroll
    for (int i = 0; i < 8; ++i) {
        int row = rg * 8 + i;
        const f32x4* xp = reinterpret_cast<const f32x4*>(x + (size_t)(m0 + row) * 1024 + c4 * 4);
        f32x4 s = {0.f, 0.f, 0.f, 0.f};
#pragma unroll
        for (int c = 0; c < 8; ++c) s += xp[c * 32];
        u16x4 o;
#pragma unroll
        for (int e = 0; e < 4; ++e) o[e] = f2bf(s[e]);
        *reinterpret_cast<u16x4*>(&Asb[row * LDA + c4 * 4]) = o;
        colp += s;
    }
    // block-reduce ts0: shfl rg-pairs, stash per-wave, one atomic per column
#pragma unroll
    for (int e = 0; e < 4; ++e) colp[e] += __shfl_xor(colp[e], 32);
    if (lane < 32) {
#pragma unroll
        for (int e = 0; e < 4; ++e) red0[wave][c4][e] = colp[e];
    }

    const int q = lane >> 4, r = lane & 15;
    const int wc = wave & 3, wr = wave >> 2;
    f32x4 acc[4][4];
#pragma unroll
    for (int i = 0; i < 4; ++i)
#pragma unroll
        for (int j = 0; j < 4; ++j) acc[i][j] = (f32x4){0.f, 0.f, 0.f, 0.f};

    __syncthreads();                         // Asb + red0 + Bsb(s2=0) all ready
    if (tid < 128) {
        float v = 0.f;
#pragma unroll
        for (int w = 0; w < 8; ++w) v += red0[w][tid >> 2][tid & 3];
        atomicAdd(&ts0[tree * 128 + tid], v);
    }

#pragma unroll
    for (int s2 = 0; s2 < 2; ++s2) {
        if (s2) {
            __syncthreads();                 // MFMA(s2=0) done reading Bsb
            stage_B_swz(Wt + 64, 128, Bsb);
            __syncthreads();                 // Bsb(s2=1) ready
        }
#pragma unroll
        for (int s = 0; s < 2; ++s) {
            bf16x8 a[4], b[4];
#pragma unroll
            for (int i = 0; i < 4; ++i)
                a[i] = *reinterpret_cast<const bf16x8*>(&Asb[(wr * 64 + i * 16 + r) * LDA + s2 * 64 + s * 32 + q * 8]);
#pragma unroll
            for (int j = 0; j < 4; ++j)
                b[j] = *reinterpret_cast<const bf16x8*>(&Bsb[BSWZ(wc * 64 + j * 16 + r, s, q, r)]);
#pragma unroll
            for (int i = 0; i < 4; ++i)
#pragma unroll
                for (int j = 0; j < 4; ++j)
                    acc[i][j] = __builtin_amdgcn_mfma_f32_16x16x32_bf16(a[i], b[j], acc[i][j], 0, 0, 0);
        }
    }
    float sj[4], s2j[4];
#pragma unroll
    for (int j = 0; j < 4; ++j) {
        float bj = bias[wc * 64 + j * 16 + r];
        float s = 0.f, s2 = 0.f;
#pragma unroll
        for (int i = 0; i < 4; ++i)
#pragma unroll
            for (int e = 0; e < 4; ++e) {
                acc[i][j][e] += bj;
                float v = acc[i][j][e];
                s += v; s2 += v * v;
            }
        s  += __shfl_xor(s, 16);  s  += __shfl_xor(s, 32);
        s2 += __shfl_xor(s2, 16); s2 += __shfl_xor(s2, 32);
        sj[j] = s; s2j[j] = s2;
    }
#pragma unroll
    for (int i = 0; i < 4; ++i)
#pragma unroll
        for (int e = 0; e < 4; ++e) {
            size_t row = m0 + wr * 64 + i * 16 + q * 4 + e;
#pragma unroll
            for (int j = 0; j < 4; ++j)
                Z1[row * 256 + wc * 64 + j * 16 + r] = f2bf(acc[i][j][e]);
        }
    if (q == 0) {
        int slot = blockIdx.x & (NSLOT - 1);
#pragma unroll
        for (int j = 0; j < 4; ++j) {
            int col = wc * 64 + j * 16 + r;
            atomicAdd(&stat_partials[slot * 512 + col], sj[j]);
            atomicAdd(&stat_partials[slot * 512 + 256 + col], s2j[j]);
        }
    }
}

// ---------- G1B: 128-row MFMA GEMM with BN on A (K=256) ----------
__global__ __launch_bounds__(512, 4) void gemm1b_kernel(const unsigned short* __restrict__ A,
                                                        const float* __restrict__ partials_in,
                                                        const float* __restrict__ bn_g,
                                                        const float* __restrict__ bn_b,
                                                        const unsigned short* __restrict__ Wt,
                                                        const float* __restrict__ bias,
                                                        unsigned short* __restrict__ C,
                                                        float* __restrict__ stat_partials) {
    constexpr int LDA = 72;
    __shared__ unsigned short Asb[128 * LDA];
    __shared__ unsigned short Bsb[256 * 64];
    __shared__ float sc_lds[256], sh_lds[256];
    const int tid = threadIdx.x;
    bn_prologue(tid, partials_in, bn_g, bn_b, 1.f / N1, sc_lds, sh_lds);
    __syncthreads();
    const int m0 = blockIdx.x * 128;
    const int wave = tid >> 6, lane = tid & 63;
    const int q = lane >> 4, r = lane & 15;
    const int wc = wave & 3, wr = wave >> 2;

    f32x4 acc[4][4];
#pragma unroll
    for (int i = 0; i < 4; ++i)
#pragma unroll
        for (int j = 0; j < 4; ++j) acc[i][j] = (f32x4){0.f, 0.f, 0.f, 0.f};

    for (int k0 = 0; k0 < 256; k0 += 64) {
        stage_B_swz(Wt + k0, 256, Bsb);
#pragma unroll
        for (int i = 0; i < 2; ++i) {
            int v = tid + i * 512;
            int row = v >> 3, kc = v & 7;
            u16x8 d = *reinterpret_cast<const u16x8*>(A + (size_t)(m0 + row) * 256 + k0 + kc * 8);
            u16x8 o;
#pragma unroll
            for (int e = 0; e < 8; ++e) {
                int k = k0 + kc * 8 + e;
                float f = sc_lds[k] * bf2f(d[e]) + sh_lds[k];
                o[e] = f2bf(f > 0.f ? f : 0.f);
            }
            *reinterpret_cast<u16x8*>(&Asb[row * LDA + kc * 8]) = o;
        }
        __syncthreads();
#pragma unroll
        for (int s = 0; s < 2; ++s) {
            bf16x8 a[4], b[4];
#pragma unroll
            for (int i = 0; i < 4; ++i)
                a[i] = *reinterpret_cast<const bf16x8*>(&Asb[(wr * 64 + i * 16 + r) * LDA + s * 32 + q * 8]);
#pragma unroll
            for (int j = 0; j < 4; ++j)
                b[j] = *reinterpret_cast<const bf16x8*>(&Bsb[BSWZ(wc * 64 + j * 16 + r, s, q, r)]);
#pragma unroll
            for (int i = 0; i < 4; ++i)
#pragma unroll
                for (int j = 0; j < 4; ++j)
                    acc[i][j] = __builtin_amdgcn_mfma_f32_16x16x32_bf16(a[i], b[j], acc[i][j], 0, 0, 0);
        }
        __syncthreads();
    }
    float sj[4], s2j[4];
#pragma unroll
    for (int j = 0; j < 4; ++j) {
        float bj = bias[wc * 64 + j * 16 + r];
        float s = 0.f, s2 = 0.f;
#pragma unroll
        for (int i = 0; i < 4; ++i)
#pragma unroll
            for (int e = 0; e < 4; ++e) {
                acc[i][j][e] += bj;
                float v = acc[i][j][e];
                s += v; s2 += v * v;
            }
        s  += __shfl_xor(s, 16);  s  += __shfl_xor(s, 32);
        s2 += __shfl_xor(s2, 16); s2 += __shfl_xor(s2, 32);
        sj[j] = s; s2j[j] = s2;
    }
#pragma unroll
    for (int i = 0; i < 4; ++i)
#pragma unroll
        for (int e = 0; e < 4; ++e) {
            size_t row = m0 + wr * 64 + i * 16 + q * 4 + e;
#pragma unroll
            for (int j = 0; j < 4; ++j)
                C[row * 256 + wc * 64 + j * 16 + r] = f2bf(acc[i][j][e]);
        }
    if (q == 0) {
        int slot = blockIdx.x & (NSLOT - 1);
#pragma unroll
        for (int j = 0; j < 4; ++j) {
            int col = wc * 64 + j * 16 + r;
            atomicAdd(&stat_partials[slot * 512 + col], sj[j]);
            atomicAdd(&stat_partials[slot * 512 + 256 + col], s2j[j]);
        }
    }
}

// ---------- shared 32-row GEMM pieces (K=256, swizzled B via global_load_lds) ----------
__device__ __forceinline__ void gemm32_kloop(const unsigned short* __restrict__ Wt,
                                             const float* __restrict__ bias,
                                             unsigned short* __restrict__ C,
                                             float* __restrict__ statsOut,
                                             int m0, int slot,
                                             const unsigned short* Asb, unsigned short* Bsb) {
    const int tid = threadIdx.x, wave = tid >> 6, lane = tid & 63;
    const int q = lane >> 4, r = lane & 15;
    const int wc = wave & 3, wr = wave >> 2;   // wr 0..1: rows wr*16+r
    f32x4 acc[4];
#pragma unroll
    for (int j = 0; j < 4; ++j) acc[j] = (f32x4){0.f, 0.f, 0.f, 0.f};
    for (int kt = 0; kt < 4; ++kt) {
        stage_B_swz(Wt + kt * 64, 256, Bsb);
        __syncthreads();
#pragma unroll
        for (int s = 0; s < 2; ++s) {
            bf16x8 a = *reinterpret_cast<const bf16x8*>(&Asb[(wr * 16 + r) * 264 + kt * 64 + s * 32 + q * 8]);
#pragma unroll
            for (int j = 0; j < 4; ++j) {
                bf16x8 b = *reinterpret_cast<const bf16x8*>(&Bsb[BSWZ(wc * 64 + j * 16 + r, s, q, r)]);
                acc[j] = __builtin_amdgcn_mfma_f32_16x16x32_bf16(a, b, acc[j], 0, 0, 0);
            }
        }
        __syncthreads();
    }
#pragma unroll
    for (int j = 0; j < 4; ++j) {
        float bj = bias[wc * 64 + j * 16 + r];
        float s = 0.f, s2 = 0.f;
#pragma unroll
        for (int e = 0; e < 4; ++e) {
            acc[j][e] += bj;
            float v = acc[j][e];
            s += v; s2 += v * v;
        }
        s  += __shfl_xor(s, 16);  s  += __shfl_xor(s, 32);
        s2 += __shfl_xor(s2, 16); s2 += __shfl_xor(s2, 32);
#pragma unroll
        for (int e = 0; e < 4; ++e)
            C[(size_t)(m0 + wr * 16 + q * 4 + e) * 256 + wc * 64 + j * 16 + r] = f2bf(acc[j][e]);
        if (q == 0) {
            int col = wc * 64 + j * 16 + r;
            atomicAdd(&statsOut[slot * 512 + col], s);
            atomicAdd(&statsOut[slot * 512 + 256 + col], s2);
        }
    }
}

__device__ __forceinline__ void stage_A32(const unsigned short* __restrict__ A, int m0,
                                          bool bn, const float* sc_lds, const float* sh_lds,
                                          unsigned short* Asb) {
    const int tid = threadIdx.x;
#pragma unroll
    for (int i = 0; i < 2; ++i) {
        int v = tid + i * 512;               // 0..1023
        int row = v >> 5, kc = v & 31;
        u16x8 d = *reinterpret_cast<const u16x8*>(A + (size_t)(m0 + row) * 256 + kc * 8);
        if (bn) {
            u16x8 o;
#pragma unroll
            for (int e = 0; e < 8; ++e) {
                int k = kc * 8 + e;
                float f = sc_lds[k] * bf2f(d[e]) + sh_lds[k];
                o[e] = f2bf(f > 0.f ? f : 0.f);
            }
            d = o;
        }
        *reinterpret_cast<u16x8*>(&Asb[row * 264 + kc * 8]) = d;
    }
}

// ---------- G2A: pool8(relu(bn(Z2))) -> 32-row A, exact ts1, @ lw1[0] (256 blocks) ----
__global__ __launch_bounds__(512, 4) void gemm2a_kernel(const unsigned short* __restrict__ Z2,
                                                        const float* __restrict__ partials_in,
                                                        const float* __restrict__ g,
                                                        const float* __restrict__ b,
                                                        const unsigned short* __restrict__ Wt2,
                                                        const float* __restrict__ bias,
                                                        unsigned short* __restrict__ Z2a,
                                                        float* __restrict__ statsOut,
                                                        float* __restrict__ ts1) {
    __shared__ unsigned short Asb[32 * 264];
    __shared__ unsigned short Bsb[256 * 64];
    __shared__ float scsh[512];
    const int tid = threadIdx.x, bid = blockIdx.x;
    bn_prologue(tid, partials_in, g, b, 1.f / N1, scsh, scsh + 256);
    __syncthreads();
    const int c8 = tid & 31, rg = tid >> 5;   // rg 0..15, 2 rows each
    const int m0 = bid * 32, d0 = c8 * 8;
    float sc[8], sh[8], colp[8];
#pragma unroll
    for (int e = 0; e < 8; ++e) { sc[e] = scsh[d0 + e]; sh[e] = scsh[256 + d0 + e]; colp[e] = 0.f; }
#pragma unroll
    for (int i = 0; i < 2; ++i) {
        int row = rg * 2 + i;
        float s[8];
#pragma unroll
        for (int e = 0; e < 8; ++e) s[e] = 0.f;
#pragma unroll
        for (int c = 0; c < 8; ++c) {
            u16x8 z = *reinterpret_cast<const u16x8*>(Z2 + ((size_t)(m0 + row) * 8 + c) * 256 + d0);
#pragma unroll
            for (int e = 0; e < 8; ++e) {
                float f = sc[e] * bf2f(z[e]) + sh[e];
                s[e] += f > 0.f ? f : 0.f;
            }
        }
        u16x8 o;
#pragma unroll
        for (int e = 0; e < 8; ++e) { o[e] = f2bf(s[e]); colp[e] += s[e]; }
        *reinterpret_cast<u16x8*>(&Asb[row * 264 + d0]) = o;
    }
    float* red = (float*)Bsb;                 // [16][256] scratch before B staging
#pragma unroll
    for (int e = 0; e < 8; ++e) red[rg * 256 + d0 + e] = colp[e];
    __syncthreads();
    if (tid < 256) {
        float t = 0.f;
#pragma unroll
        for (int gi = 0; gi < 16; ++gi) t += red[gi * 256 + tid];
        ts1[bid * 256 + tid] = t;             // exact: 1 tree per block
    }
    __syncthreads();
    gemm32_kloop(Wt2, bias, Z2a, statsOut, m0, bid & (NSLOT - 1), Asb, Bsb);
}

// ---------- G2B/G3B: relu(bn(A)) @ W (32-row tiles) ----------
__global__ __launch_bounds__(512, 4) void gemm_bn32_kernel(const unsigned short* __restrict__ A,
                                                           const float* __restrict__ partials_in,
                                                           const float* __restrict__ g,
                                                           const float* __restrict__ b,
                                                           float invM,
                                                           const unsigned short* __restrict__ W,
                                                           const float* __restrict__ bias,
                                                           unsigned short* __restrict__ C,
                                                           float* __restrict__ statsOut) {
    __shared__ unsigned short Asb[32 * 264];
    __shared__ unsigned short Bsb[256 * 64];
    __shared__ float scsh[512];
    const int tid = threadIdx.x, bid = blockIdx.x;
    bn_prologue(tid, partials_in, g, b, invM, scsh, scsh + 256);
    __syncthreads();
    stage_A32(A, bid * 32, true, scsh, scsh + 256, Asb);
    __syncthreads();
    gemm32_kloop(W, bias, C, statsOut, bid * 32, bid & (NSLOT - 1), Asb, Bsb);
}

// ---------- G3A: pool32(relu(bn(Z2b))) -> A + pooled3 write, @ lw1[1] (8 blocks) ------
__global__ __launch_bounds__(512, 4) void gemm3a_kernel(const unsigned short* __restrict__ Z2b,
                                                        const float* __restrict__ partials_in,
                                                        const float* __restrict__ g,
                                                        const float* __restrict__ b,
                                                        const unsigned short* __restrict__ W,
                                                        const float* __restrict__ bias,
                                                        unsigned short* __restrict__ pooled3,
                                                        unsigned short* __restrict__ Z3a,
                                                        float* __restrict__ statsOut) {
    __shared__ unsigned short Asb[32 * 264];
    __shared__ unsigned short Bsb[256 * 64];
    __shared__ float scsh[512];
    const int tid = threadIdx.x, bid = blockIdx.x;
    bn_prologue(tid, partials_in, g, b, 1.f / N2, scsh, scsh + 256);
    __syncthreads();
    const int c8 = tid & 31, rg = tid >> 5;   // rg 0..15, 2 rows each
    const int m0 = bid * 32, d0 = c8 * 8;
    float sc[8], sh[8];
#pragma unroll
    for (int e = 0; e < 8; ++e) { sc[e] = scsh[d0 + e]; sh[e] = scsh[256 + d0 + e]; }
#pragma unroll
    for (int i = 0; i < 2; ++i) {
        int row = rg * 2 + i;                 // pooled3 row within block: 0..31
        float s[8];
#pragma unroll
        for (int e = 0; e < 8; ++e) s[e] = 0.f;
        for (int gi = 0; gi < 32; ++gi) {
            u16x8 z = *reinterpret_cast<const u16x8*>(Z2b + ((size_t)(m0 + row) * 32 + gi) * 256 + d0);
#pragma unroll
            for (int e = 0; e < 8; ++e) {
                float f = sc[e] * bf2f(z[e]) + sh[e];
                s[e] += f > 0.f ? f : 0.f;
            }
        }
        u16x8 o;
#pragma unroll
        for (int e = 0; e < 8; ++e) o[e] = f2bf(s[e]);
        *reinterpret_cast<u16x8*>(&Asb[row * 264 + d0]) = o;
        *reinterpret_cast<u16x8*>(pooled3 + (size_t)(m0 + row) * 256 + d0) = o;
    }
    __syncthreads();
    gemm32_kloop(W, bias, Z3a, statsOut, m0, bid & (NSLOT - 1), Asb, Bsb);
}

// ---------- readout heads (bn from slot-5 partials) ----------
__global__ __launch_bounds__(256) void head_kernel(const float* __restrict__ ts0,
                                                   const float* __restrict__ ts1,
                                                   const unsigned short* __restrict__ p3,
                                                   const unsigned short* __restrict__ Z3b,
                                                   const float* __restrict__ partials,
                                                   const float* __restrict__ g,
                                                   const float* __restrict__ b,
                                                   const float* __restrict__ p0w,
                                                   const float* __restrict__ p0b,
                                                   const float* __restrict__ phw,
                                                   const float* __restrict__ phb,
                                                   float* __restrict__ out) {
    __shared__ float scsh[512];
    int t = blockIdx.x, d = threadIdx.x;
    bn_prologue(d, partials, g, b, 1.f / NB, scsh, scsh + 256);
    __syncthreads();
    float acc[10];
#pragma unroll
    for (int o = 0; o < 10; ++o) acc[o] = 0.f;
    if (d < 128) {
        float v = ts0[t * 128 + d];
#pragma unroll
        for (int o = 0; o < 10; ++o) acc[o] += v * p0w[d * 10 + o];
    }
    {
        float v = ts1[t * 256 + d];
#pragma unroll
        for (int o = 0; o < 10; ++o) acc[o] += v * phw[d * 10 + o];
    }
    {
        float v = bf2f(p3[t * 256 + d]);
#pragma unroll
        for (int o = 0; o < 10; ++o) acc[o] += v * phw[2560 + d * 10 + o];
    }
    {
        float v = scsh[d] * bf2f(Z3b[t * 256 + d]) + scsh[256 + d];
        v = v > 0.f ? v : 0.f;
#pragma unroll
        for (int o = 0; o < 10; ++o) acc[o] += v * phw[5120 + d * 10 + o];
    }
    __shared__ float red[256];
    for (int o = 0; o < 10; ++o) {
        red[d] = acc[o];
        __syncthreads();
        for (int s = 128; s > 0; s >>= 1) {
            if (d < s) red[d] += red[d + s];
            __syncthreads();
        }
        if (d == 0) out[t * 10 + o] = red[0] + p0b[o] + phb[o] + phb[10 + o] + phb[20 + o];
        __syncthreads();
    }
}

extern "C" void kernel_launch(void* const* d_in, const int* in_sizes, int n_in,
                              void* d_out, int out_size, void* d_ws, size_t ws_size,
                              hipStream_t stream) {
    const float* x       = (const float*)d_in[0];
    const float* l1_w1   = (const float*)d_in[7];
    const float* l1_b1   = (const float*)d_in[8];
    const float* l1_bn1g = (const float*)d_in[9];
    const float* l1_bn1b = (const float*)d_in[10];
    const float* l1_w2   = (const float*)d_in[11];
    const float* l1_b2   = (const float*)d_in[12];
    const float* l1_bng  = (const float*)d_in[13];
    const float* l1_bnb  = (const float*)d_in[14];
    const float* lw1     = (const float*)d_in[15];
    const float* lb1     = (const float*)d_in[16];
    const float* lbn1g   = (const float*)d_in[17];
    const float* lbn1b   = (const float*)d_in[18];
    const float* lw2     = (const float*)d_in[19];
    const float* lb2     = (const float*)d_in[20];
    const float* lbng    = (const float*)d_in[21];
    const float* lbnb    = (const float*)d_in[22];
    const float* pred0_w = (const float*)d_in[23];
    const float* pred0_b = (const float*)d_in[24];
    const float* predh_w = (const float*)d_in[25];
    const float* predh_b = (const float*)d_in[26];
    float* out = (float*)d_out;

    uint8_t* wsb = (uint8_t*)d_ws;
    unsigned short* Z1      = (unsigned short*)(wsb + (16ull << 20));
    unsigned short* Z2      = (unsigned short*)(wsb + (48ull << 20));
    unsigned short* Z2a     = (unsigned short*)(wsb + (84ull << 20));
    unsigned short* Z2b     = (unsigned short*)(wsb + (88ull << 20));
    unsigned short* pooled3 = (unsigned short*)(wsb + (92ull << 20));
    unsigned short* Z3a     = (unsigned short*)(wsb + (92ull << 20) + 131072);
    unsigned short* Z3b     = (unsigned short*)(wsb + (92ull << 20) + 262144);
    unsigned short* Wt      = (unsigned short*)(wsb + (93ull << 20));
    float* zbase = (float*)(wsb + (94ull << 20));
    float* ts0   = zbase;                        // 32768 f32 (atomic -> zeroed)
    float* ts1   = zbase + 32768;                // 65536 f32 (exact stores)
    float* stats = zbase + 32768 + 65536;        // 6 x [NSLOT][512] f32
    auto SP = [&](int i) { return stats + i * (NSLOT * 512); };
    size_t zbytes = (32768 + 65536 + 6 * NSLOT * 512) * sizeof(float);

    hipMemsetAsync(zbase, 0, zbytes, stream);
    transpose_weights<<<352, 256, 0, stream>>>(l1_w1, l1_w2, lw1, lw2, Wt);

    // layer 1
    gemm1_fused<<<N1 / 128, 512, 0, stream>>>(x, Wt, l1_b1, Z1, SP(0), ts0);
    gemm1b_kernel<<<N1 / 128, 512, 0, stream>>>(
        Z1, SP(0), l1_bn1g, l1_bn1b, Wt + 32768, l1_b2, Z2, SP(1));

    // layer 2
    gemm2a_kernel<<<N2 / 32, 512, 0, stream>>>(
        Z2, SP(1), l1_bng, l1_bnb, Wt + 98304, lb1, Z2a, SP(2), ts1);
    gemm_bn32_kernel<<<N2 / 32, 512, 0, stream>>>(
        Z2a, SP(2), lbn1g, lbn1b, 1.f / N2, Wt + 163840, lb2, Z2b, SP(3));

    // layer 3 (8 blocks each; G3A pools 32 from Z2b and emits pooled3)
    gemm3a_kernel<<<NB / 32, 512, 0, stream>>>(
        Z2b, SP(3), lbng, lbnb, Wt + 229376, lb1 + 256, pooled3, Z3a, SP(4));
    gemm_bn32_kernel<<<NB / 32, 512, 0, stream>>>(
        Z3a, SP(4), lbn1g + 256, lbn1b + 256, 1.f / NB, Wt + 294912, lb2 + 256, Z3b, SP(5));

    // readout
    head_kernel<<<NB, 256, 0, stream>>>(ts0, ts1, pooled3, Z3b, SP(5),
                                        lbng + 256, lbnb + 256,
                                        pred0_w, pred0_b, predh_w, predh_b, out);
}

// Round 14
// 157.352 us; speedup vs baseline: 1.0488x; 1.0488x over previous
//
#include <hip/hip_runtime.h>
#include <hip/hip_bf16.h>

// TreeCNN on MI355X — bf16 MFMA, split-kernel structure (serial BN chain).
// R14 = revert to R12 (best: 161 us). B-tiles via global_load_lds w/ XOR-swizzled
// source; pools fused into GEMM A-stages; BN finalize fused into consumer prologues.
// 9 dispatches: memset, transpose, G1A, G1B, G2A(pool8+ts1), G2B, G3A(pool32), G3B, head.

#define N0 (256*2048)
#define N1 (256*256)
#define N2 (256*32)
#define NB 256
#define BN_EPS 1e-5f
#define NSLOT 8

typedef __attribute__((ext_vector_type(8))) __bf16 bf16x8;
typedef __attribute__((ext_vector_type(8))) unsigned short u16x8;
typedef __attribute__((ext_vector_type(4))) unsigned short u16x4;
typedef __attribute__((ext_vector_type(4))) float f32x4;

__device__ inline float bf2f(unsigned short b) {
    unsigned u = ((unsigned)b) << 16;
    float f; __builtin_memcpy(&f, &u, 4); return f;
}
__device__ inline unsigned short f2bf(float f) {
    unsigned u; __builtin_memcpy(&u, &f, 4);
    u += 0x7fff + ((u >> 16) & 1);
    return (unsigned short)(u >> 16);
}

// 16B async global->LDS. LDS dest is wave-uniform base + lane*16 (linear!).
__device__ __forceinline__ void gload_lds16(const void* g, void* l) {
    __builtin_amdgcn_global_load_lds((const __attribute__((address_space(1))) unsigned int*)g,
                                     (__attribute__((address_space(3))) unsigned int*)l,
                                     16, 0, 0);
}

// Stage B-tile [256 rows][64 k-shorts] from Wt(+ktile) with XOR-swizzle:
// LDS[n][p] = B[n][p ^ (n&7)] (granule = 16B). 512 threads, 8 waves, 4 iters.
__device__ __forceinline__ void stage_B_swz(const unsigned short* __restrict__ Wsrc,
                                            int K, unsigned short* Bsb) {
    const int wave = threadIdx.x >> 6, lane = threadIdx.x & 63;
#pragma unroll
    for (int i = 0; i < 4; ++i) {
        int gbase = (wave * 4 + i) * 64;     // wave-uniform granule base
        int idx = gbase + lane;              // this lane's granule
        int n = idx >> 3, p = idx & 7;
        gload_lds16(Wsrc + (size_t)n * K + ((p ^ (n & 7)) << 3), &Bsb[gbase * 8]);
    }
}

// Swizzled B read: logical granule g = s*4+q, physical = g ^ (r&7). Row stride 64 shorts.
#define BSWZ(row, s, q, r) (((row) * 64) + ((((s) * 4 + (q)) ^ ((r) & 7)) << 3))

// ---------- weights: LDS-tiled transpose + f32->bf16, Wt[n][k] ----------
__global__ __launch_bounds__(256) void transpose_weights(const float* __restrict__ l1_w1,
                                                         const float* __restrict__ l1_w2,
                                                         const float* __restrict__ lw1,
                                                         const float* __restrict__ lw2,
                                                         unsigned short* __restrict__ Wt) {
    __shared__ float t[32][33];
    const int bid = blockIdx.x;
    const float* src; unsigned short* dst; int K, tile;
    if (bid < 32)        { src = l1_w1;         dst = Wt;          K = 128; tile = bid; }
    else if (bid < 96)   { src = l1_w2;         dst = Wt + 32768;  K = 256; tile = bid - 32; }
    else if (bid < 160)  { src = lw1;           dst = Wt + 98304;  K = 256; tile = bid - 96; }
    else if (bid < 224)  { src = lw2;           dst = Wt + 163840; K = 256; tile = bid - 160; }
    else if (bid < 288)  { src = lw1 + 65536;   dst = Wt + 229376; K = 256; tile = bid - 224; }
    else                 { src = lw2 + 65536;   dst = Wt + 294912; K = 256; tile = bid - 288; }
    const int ti = tile >> 3, tj = tile & 7;   // k-tile, n-tile
    const int lx = threadIdx.x & 31, ly = threadIdx.x >> 5;
#pragma unroll
    for (int i = 0; i < 4; ++i) {
        int k = ti * 32 + ly + i * 8;
        t[ly + i * 8][lx] = src[(size_t)k * 256 + tj * 32 + lx];
    }
    __syncthreads();
#pragma unroll
    for (int i = 0; i < 4; ++i) {
        int n = tj * 32 + ly + i * 8;
        dst[(size_t)n * K + ti * 32 + lx] = f2bf(t[lx][ly + i * 8]);
    }
}

// ---------- BN finalize prologue (8-slot partials -> scale/shift in LDS) ----------
__device__ __forceinline__ void bn_prologue(int tid, const float* __restrict__ partials,
                                            const float* __restrict__ g, const float* __restrict__ b,
                                            float invM, float* sc_lds, float* sh_lds) {
    if (tid < 256) {
        float s = 0.f, s2 = 0.f;
#pragma unroll
        for (int k = 0; k < NSLOT; ++k) {
            s  += partials[k * 512 + tid];
            s2 += partials[k * 512 + 256 + tid];
        }
        float mean = s * invM;
        float var = s2 * invM - mean * mean;
        float sc = g[tid] * rsqrtf(var + BN_EPS);
        sc_lds[tid] = sc;
        sh_lds[tid] = b[tid] - mean * sc;
    }
}

// ---------- G1A: x -> pool8(f32) -> A-tile @ W1 -> Z1; fused ts0 + stats ----------
__global__ __launch_bounds__(512, 4) void gemm1_fused(const float* __restrict__ x,
                                                      const unsigned short* __restrict__ Wt,
                                                      const float* __restrict__ bias,
                                                      unsigned short* __restrict__ Z1,
                                                      float* __restrict__ stat_partials,
                                                      float* __restrict__ ts0) {
    constexpr int LDA = 136;
    __shared__ unsigned short Asb[128 * LDA];
    __shared__ unsigned short Bsb[256 * 64];
    const int tid = threadIdx.x;
    const int c4 = tid & 31, rg = tid >> 5;
    const int m0 = blockIdx.x * 128;
    const int tree = blockIdx.x >> 1;
    f32x4 colp = {0.f, 0.f, 0.f, 0.f};
#pragma unroll
    for (int i = 0; i < 8; ++i) {
        int row = rg * 8 + i;
        const f32x4* xp = reinterpret_cast<const f32x4*>(x + (size_t)(m0 + row) * 1024 + c4 * 4);
        f32x4 s = {0.f, 0.f, 0.f, 0.f};
#pragma unroll
        for (int c = 0; c < 8; ++c) s += xp[c * 32];
        u16x4 o;
#pragma unroll
        for (int e = 0; e < 4; ++e) o[e] = f2bf(s[e]);
        *reinterpret_cast<u16x4*>(&Asb[row * LDA + c4 * 4]) = o;
        colp += s;
    }
#pragma unroll
    for (int e = 0; e < 4; ++e) atomicAdd(&ts0[tree * 128 + c4 * 4 + e], colp[e]);

    const int wave = tid >> 6, lane = tid & 63;
    const int q = lane >> 4, r = lane & 15;
    const int wc = wave & 3, wr = wave >> 2;
    f32x4 acc[4][4];
#pragma unroll
    for (int i = 0; i < 4; ++i)
#pragma unroll
        for (int j = 0; j < 4; ++j) acc[i][j] = (f32x4){0.f, 0.f, 0.f, 0.f};

#pragma unroll
    for (int s2 = 0; s2 < 2; ++s2) {
        stage_B_swz(Wt + s2 * 64, 128, Bsb);
        __syncthreads();
#pragma unroll
        for (int s = 0; s < 2; ++s) {
            bf16x8 a[4], b[4];
#pragma unroll
            for (int i = 0; i < 4; ++i)
                a[i] = *reinterpret_cast<const bf16x8*>(&Asb[(wr * 64 + i * 16 + r) * LDA + s2 * 64 + s * 32 + q * 8]);
#pragma unroll
            for (int j = 0; j < 4; ++j)
                b[j] = *reinterpret_cast<const bf16x8*>(&Bsb[BSWZ(wc * 64 + j * 16 + r, s, q, r)]);
#pragma unroll
            for (int i = 0; i < 4; ++i)
#pragma unroll
                for (int j = 0; j < 4; ++j)
                    acc[i][j] = __builtin_amdgcn_mfma_f32_16x16x32_bf16(a[i], b[j], acc[i][j], 0, 0, 0);
        }
        __syncthreads();
    }
    float sj[4], s2j[4];
#pragma unroll
    for (int j = 0; j < 4; ++j) {
        float bj = bias[wc * 64 + j * 16 + r];
        float s = 0.f, s2 = 0.f;
#pragma unroll
        for (int i = 0; i < 4; ++i)
#pragma unroll
            for (int e = 0; e < 4; ++e) {
                acc[i][j][e] += bj;
                float v = acc[i][j][e];
                s += v; s2 += v * v;
            }
        s  += __shfl_xor(s, 16);  s  += __shfl_xor(s, 32);
        s2 += __shfl_xor(s2, 16); s2 += __shfl_xor(s2, 32);
        sj[j] = s; s2j[j] = s2;
    }
#pragma unroll
    for (int i = 0; i < 4; ++i)
#pragma unroll
        for (int e = 0; e < 4; ++e) {
            size_t row = m0 + wr * 64 + i * 16 + q * 4 + e;
#pragma unroll
            for (int j = 0; j < 4; ++j)
                Z1[row * 256 + wc * 64 + j * 16 + r] = f2bf(acc[i][j][e]);
        }
    if (q == 0) {
        int slot = blockIdx.x & (NSLOT - 1);
#pragma unroll
        for (int j = 0; j < 4; ++j) {
            int col = wc * 64 + j * 16 + r;
            atomicAdd(&stat_partials[slot * 512 + col], sj[j]);
            atomicAdd(&stat_partials[slot * 512 + 256 + col], s2j[j]);
        }
    }
}

// ---------- G1B: 128-row MFMA GEMM with BN on A (K=256) ----------
__global__ __launch_bounds__(512, 4) void gemm1b_kernel(const unsigned short* __restrict__ A,
                                                        const float* __restrict__ partials_in,
                                                        const float* __restrict__ bn_g,
                                                        const float* __restrict__ bn_b,
                                                        const unsigned short* __restrict__ Wt,
                                                        const float* __restrict__ bias,
                                                        unsigned short* __restrict__ C,
                                                        float* __restrict__ stat_partials) {
    constexpr int LDA = 72;
    __shared__ unsigned short Asb[128 * LDA];
    __shared__ unsigned short Bsb[256 * 64];
    __shared__ float sc_lds[256], sh_lds[256];
    const int tid = threadIdx.x;
    bn_prologue(tid, partials_in, bn_g, bn_b, 1.f / N1, sc_lds, sh_lds);
    __syncthreads();
    const int m0 = blockIdx.x * 128;
    const int wave = tid >> 6, lane = tid & 63;
    const int q = lane >> 4, r = lane & 15;
    const int wc = wave & 3, wr = wave >> 2;

    f32x4 acc[4][4];
#pragma unroll
    for (int i = 0; i < 4; ++i)
#pragma unroll
        for (int j = 0; j < 4; ++j) acc[i][j] = (f32x4){0.f, 0.f, 0.f, 0.f};

    for (int k0 = 0; k0 < 256; k0 += 64) {
        stage_B_swz(Wt + k0, 256, Bsb);
#pragma unroll
        for (int i = 0; i < 2; ++i) {
            int v = tid + i * 512;
            int row = v >> 3, kc = v & 7;
            u16x8 d = *reinterpret_cast<const u16x8*>(A + (size_t)(m0 + row) * 256 + k0 + kc * 8);
            u16x8 o;
#pragma unroll
            for (int e = 0; e < 8; ++e) {
                int k = k0 + kc * 8 + e;
                float f = sc_lds[k] * bf2f(d[e]) + sh_lds[k];
                o[e] = f2bf(f > 0.f ? f : 0.f);
            }
            *reinterpret_cast<u16x8*>(&Asb[row * LDA + kc * 8]) = o;
        }
        __syncthreads();
#pragma unroll
        for (int s = 0; s < 2; ++s) {
            bf16x8 a[4], b[4];
#pragma unroll
            for (int i = 0; i < 4; ++i)
                a[i] = *reinterpret_cast<const bf16x8*>(&Asb[(wr * 64 + i * 16 + r) * LDA + s * 32 + q * 8]);
#pragma unroll
            for (int j = 0; j < 4; ++j)
                b[j] = *reinterpret_cast<const bf16x8*>(&Bsb[BSWZ(wc * 64 + j * 16 + r, s, q, r)]);
#pragma unroll
            for (int i = 0; i < 4; ++i)
#pragma unroll
                for (int j = 0; j < 4; ++j)
                    acc[i][j] = __builtin_amdgcn_mfma_f32_16x16x32_bf16(a[i], b[j], acc[i][j], 0, 0, 0);
        }
        __syncthreads();
    }
    float sj[4], s2j[4];
#pragma unroll
    for (int j = 0; j < 4; ++j) {
        float bj = bias[wc * 64 + j * 16 + r];
        float s = 0.f, s2 = 0.f;
#pragma unroll
        for (int i = 0; i < 4; ++i)
#pragma unroll
            for (int e = 0; e < 4; ++e) {
                acc[i][j][e] += bj;
                float v = acc[i][j][e];
                s += v; s2 += v * v;
            }
        s  += __shfl_xor(s, 16);  s  += __shfl_xor(s, 32);
        s2 += __shfl_xor(s2, 16); s2 += __shfl_xor(s2, 32);
        sj[j] = s; s2j[j] = s2;
    }
#pragma unroll
    for (int i = 0; i < 4; ++i)
#pragma unroll
        for (int e = 0; e < 4; ++e) {
            size_t row = m0 + wr * 64 + i * 16 + q * 4 + e;
#pragma unroll
            for (int j = 0; j < 4; ++j)
                C[row * 256 + wc * 64 + j * 16 + r] = f2bf(acc[i][j][e]);
        }
    if (q == 0) {
        int slot = blockIdx.x & (NSLOT - 1);
#pragma unroll
        for (int j = 0; j < 4; ++j) {
            int col = wc * 64 + j * 16 + r;
            atomicAdd(&stat_partials[slot * 512 + col], sj[j]);
            atomicAdd(&stat_partials[slot * 512 + 256 + col], s2j[j]);
        }
    }
}

// ---------- shared 32-row GEMM pieces (K=256, swizzled B via global_load_lds) ----------
__device__ __forceinline__ void gemm32_kloop(const unsigned short* __restrict__ Wt,
                                             const float* __restrict__ bias,
                                             unsigned short* __restrict__ C,
                                             float* __restrict__ statsOut,
                                             int m0, int slot,
                                             const unsigned short* Asb, unsigned short* Bsb) {
    const int tid = threadIdx.x, wave = tid >> 6, lane = tid & 63;
    const int q = lane >> 4, r = lane & 15;
    const int wc = wave & 3, wr = wave >> 2;   // wr 0..1: rows wr*16+r
    f32x4 acc[4];
#pragma unroll
    for (int j = 0; j < 4; ++j) acc[j] = (f32x4){0.f, 0.f, 0.f, 0.f};
    for (int kt = 0; kt < 4; ++kt) {
        stage_B_swz(Wt + kt * 64, 256, Bsb);
        __syncthreads();
#pragma unroll
        for (int s = 0; s < 2; ++s) {
            bf16x8 a = *reinterpret_cast<const bf16x8*>(&Asb[(wr * 16 + r) * 264 + kt * 64 + s * 32 + q * 8]);
#pragma unroll
            for (int j = 0; j < 4; ++j) {
                bf16x8 b = *reinterpret_cast<const bf16x8*>(&Bsb[BSWZ(wc * 64 + j * 16 + r, s, q, r)]);
                acc[j] = __builtin_amdgcn_mfma_f32_16x16x32_bf16(a, b, acc[j], 0, 0, 0);
            }
        }
        __syncthreads();
    }
#pragma unroll
    for (int j = 0; j < 4; ++j) {
        float bj = bias[wc * 64 + j * 16 + r];
        float s = 0.f, s2 = 0.f;
#pragma unroll
        for (int e = 0; e < 4; ++e) {
            acc[j][e] += bj;
            float v = acc[j][e];
            s += v; s2 += v * v;
        }
        s  += __shfl_xor(s, 16);  s  += __shfl_xor(s, 32);
        s2 += __shfl_xor(s2, 16); s2 += __shfl_xor(s2, 32);
#pragma unroll
        for (int e = 0; e < 4; ++e)
            C[(size_t)(m0 + wr * 16 + q * 4 + e) * 256 + wc * 64 + j * 16 + r] = f2bf(acc[j][e]);
        if (q == 0) {
            int col = wc * 64 + j * 16 + r;
            atomicAdd(&statsOut[slot * 512 + col], s);
            atomicAdd(&statsOut[slot * 512 + 256 + col], s2);
        }
    }
}

__device__ __forceinline__ void stage_A32(const unsigned short* __restrict__ A, int m0,
                                          bool bn, const float* sc_lds, const float* sh_lds,
                                          unsigned short* Asb) {
    const int tid = threadIdx.x;
#pragma unroll
    for (int i = 0; i < 2; ++i) {
        int v = tid + i * 512;               // 0..1023
        int row = v >> 5, kc = v & 31;
        u16x8 d = *reinterpret_cast<const u16x8*>(A + (size_t)(m0 + row) * 256 + kc * 8);
        if (bn) {
            u16x8 o;
#pragma unroll
            for (int e = 0; e < 8; ++e) {
                int k = kc * 8 + e;
                float f = sc_lds[k] * bf2f(d[e]) + sh_lds[k];
                o[e] = f2bf(f > 0.f ? f : 0.f);
            }
            d = o;
        }
        *reinterpret_cast<u16x8*>(&Asb[row * 264 + kc * 8]) = d;
    }
}

// ---------- G2A: pool8(relu(bn(Z2))) -> 32-row A, exact ts1, @ lw1[0] (256 blocks) ----
__global__ __launch_bounds__(512, 4) void gemm2a_kernel(const unsigned short* __restrict__ Z2,
                                                        const float* __restrict__ partials_in,
                                                        const float* __restrict__ g,
                                                        const float* __restrict__ b,
                                                        const unsigned short* __restrict__ Wt2,
                                                        const float* __restrict__ bias,
                                                        unsigned short* __restrict__ Z2a,
                                                        float* __restrict__ statsOut,
                                                        float* __restrict__ ts1) {
    __shared__ unsigned short Asb[32 * 264];
    __shared__ unsigned short Bsb[256 * 64];
    __shared__ float scsh[512];
    const int tid = threadIdx.x, bid = blockIdx.x;
    bn_prologue(tid, partials_in, g, b, 1.f / N1, scsh, scsh + 256);
    __syncthreads();
    const int c8 = tid & 31, rg = tid >> 5;   // rg 0..15, 2 rows each
    const int m0 = bid * 32, d0 = c8 * 8;
    float sc[8], sh[8], colp[8];
#pragma unroll
    for (int e = 0; e < 8; ++e) { sc[e] = scsh[d0 + e]; sh[e] = scsh[256 + d0 + e]; colp[e] = 0.f; }
#pragma unroll
    for (int i = 0; i < 2; ++i) {
        int row = rg * 2 + i;
        float s[8];
#pragma unroll
        for (int e = 0; e < 8; ++e) s[e] = 0.f;
#pragma unroll
        for (int c = 0; c < 8; ++c) {
            u16x8 z = *reinterpret_cast<const u16x8*>(Z2 + ((size_t)(m0 + row) * 8 + c) * 256 + d0);
#pragma unroll
            for (int e = 0; e < 8; ++e) {
                float f = sc[e] * bf2f(z[e]) + sh[e];
                s[e] += f > 0.f ? f : 0.f;
            }
        }
        u16x8 o;
#pragma unroll
        for (int e = 0; e < 8; ++e) { o[e] = f2bf(s[e]); colp[e] += s[e]; }
        *reinterpret_cast<u16x8*>(&Asb[row * 264 + d0]) = o;
    }
    float* red = (float*)Bsb;                 // [16][256] scratch before B staging
#pragma unroll
    for (int e = 0; e < 8; ++e) red[rg * 256 + d0 + e] = colp[e];
    __syncthreads();
    if (tid < 256) {
        float t = 0.f;
#pragma unroll
        for (int gi = 0; gi < 16; ++gi) t += red[gi * 256 + tid];
        ts1[bid * 256 + tid] = t;             // exact: 1 tree per block
    }
    __syncthreads();
    gemm32_kloop(Wt2, bias, Z2a, statsOut, m0, bid & (NSLOT - 1), Asb, Bsb);
}

// ---------- G2B/G3B: relu(bn(A)) @ W (32-row tiles) ----------
__global__ __launch_bounds__(512, 4) void gemm_bn32_kernel(const unsigned short* __restrict__ A,
                                                           const float* __restrict__ partials_in,
                                                           const float* __restrict__ g,
                                                           const float* __restrict__ b,
                                                           float invM,
                                                           const unsigned short* __restrict__ W,
                                                           const float* __restrict__ bias,
                                                           unsigned short* __restrict__ C,
                                                           float* __restrict__ statsOut) {
    __shared__ unsigned short Asb[32 * 264];
    __shared__ unsigned short Bsb[256 * 64];
    __shared__ float scsh[512];
    const int tid = threadIdx.x, bid = blockIdx.x;
    bn_prologue(tid, partials_in, g, b, invM, scsh, scsh + 256);
    __syncthreads();
    stage_A32(A, bid * 32, true, scsh, scsh + 256, Asb);
    __syncthreads();
    gemm32_kloop(W, bias, C, statsOut, bid * 32, bid & (NSLOT - 1), Asb, Bsb);
}

// ---------- G3A: pool32(relu(bn(Z2b))) -> A + pooled3 write, @ lw1[1] (8 blocks) ------
__global__ __launch_bounds__(512, 4) void gemm3a_kernel(const unsigned short* __restrict__ Z2b,
                                                        const float* __restrict__ partials_in,
                                                        const float* __restrict__ g,
                                                        const float* __restrict__ b,
                                                        const unsigned short* __restrict__ W,
                                                        const float* __restrict__ bias,
                                                        unsigned short* __restrict__ pooled3,
                                                        unsigned short* __restrict__ Z3a,
                                                        float* __restrict__ statsOut) {
    __shared__ unsigned short Asb[32 * 264];
    __shared__ unsigned short Bsb[256 * 64];
    __shared__ float scsh[512];
    const int tid = threadIdx.x, bid = blockIdx.x;
    bn_prologue(tid, partials_in, g, b, 1.f / N2, scsh, scsh + 256);
    __syncthreads();
    const int c8 = tid & 31, rg = tid >> 5;   // rg 0..15, 2 rows each
    const int m0 = bid * 32, d0 = c8 * 8;
    float sc[8], sh[8];
#pragma unroll
    for (int e = 0; e < 8; ++e) { sc[e] = scsh[d0 + e]; sh[e] = scsh[256 + d0 + e]; }
#pragma unroll
    for (int i = 0; i < 2; ++i) {
        int row = rg * 2 + i;                 // pooled3 row within block: 0..31
        float s[8];
#pragma unroll
        for (int e = 0; e < 8; ++e) s[e] = 0.f;
        for (int gi = 0; gi < 32; ++gi) {
            u16x8 z = *reinterpret_cast<const u16x8*>(Z2b + ((size_t)(m0 + row) * 32 + gi) * 256 + d0);
#pragma unroll
            for (int e = 0; e < 8; ++e) {
                float f = sc[e] * bf2f(z[e]) + sh[e];
                s[e] += f > 0.f ? f : 0.f;
            }
        }
        u16x8 o;
#pragma unroll
        for (int e = 0; e < 8; ++e) o[e] = f2bf(s[e]);
        *reinterpret_cast<u16x8*>(&Asb[row * 264 + d0]) = o;
        *reinterpret_cast<u16x8*>(pooled3 + (size_t)(m0 + row) * 256 + d0) = o;
    }
    __syncthreads();
    gemm32_kloop(W, bias, Z3a, statsOut, m0, bid & (NSLOT - 1), Asb, Bsb);
}

// ---------- readout heads (bn from slot-5 partials) ----------
__global__ __launch_bounds__(256) void head_kernel(const float* __restrict__ ts0,
                                                   const float* __restrict__ ts1,
                                                   const unsigned short* __restrict__ p3,
                                                   const unsigned short* __restrict__ Z3b,
                                                   const float* __restrict__ partials,
                                                   const float* __restrict__ g,
                                                   const float* __restrict__ b,
                                                   const float* __restrict__ p0w,
                                                   const float* __restrict__ p0b,
                                                   const float* __restrict__ phw,
                                                   const float* __restrict__ phb,
                                                   float* __restrict__ out) {
    __shared__ float scsh[512];
    int t = blockIdx.x, d = threadIdx.x;
    bn_prologue(d, partials, g, b, 1.f / NB, scsh, scsh + 256);
    __syncthreads();
    float acc[10];
#pragma unroll
    for (int o = 0; o < 10; ++o) acc[o] = 0.f;
    if (d < 128) {
        float v = ts0[t * 128 + d];
#pragma unroll
        for (int o = 0; o < 10; ++o) acc[o] += v * p0w[d * 10 + o];
    }
    {
        float v = ts1[t * 256 + d];
#pragma unroll
        for (int o = 0; o < 10; ++o) acc[o] += v * phw[d * 10 + o];
    }
    {
        float v = bf2f(p3[t * 256 + d]);
#pragma unroll
        for (int o = 0; o < 10; ++o) acc[o] += v * phw[2560 + d * 10 + o];
    }
    {
        float v = scsh[d] * bf2f(Z3b[t * 256 + d]) + scsh[256 + d];
        v = v > 0.f ? v : 0.f;
#pragma unroll
        for (int o = 0; o < 10; ++o) acc[o] += v * phw[5120 + d * 10 + o];
    }
    __shared__ float red[256];
    for (int o = 0; o < 10; ++o) {
        red[d] = acc[o];
        __syncthreads();
        for (int s = 128; s > 0; s >>= 1) {
            if (d < s) red[d] += red[d + s];
            __syncthreads();
        }
        if (d == 0) out[t * 10 + o] = red[0] + p0b[o] + phb[o] + phb[10 + o] + phb[20 + o];
        __syncthreads();
    }
}

extern "C" void kernel_launch(void* const* d_in, const int* in_sizes, int n_in,
                              void* d_out, int out_size, void* d_ws, size_t ws_size,
                              hipStream_t stream) {
    const float* x       = (const float*)d_in[0];
    const float* l1_w1   = (const float*)d_in[7];
    const float* l1_b1   = (const float*)d_in[8];
    const float* l1_bn1g = (const float*)d_in[9];
    const float* l1_bn1b = (const float*)d_in[10];
    const float* l1_w2   = (const float*)d_in[11];
    const float* l1_b2   = (const float*)d_in[12];
    const float* l1_bng  = (const float*)d_in[13];
    const float* l1_bnb  = (const float*)d_in[14];
    const float* lw1     = (const float*)d_in[15];
    const float* lb1     = (const float*)d_in[16];
    const float* lbn1g   = (const float*)d_in[17];
    const float* lbn1b   = (const float*)d_in[18];
    const float* lw2     = (const float*)d_in[19];
    const float* lb2     = (const float*)d_in[20];
    const float* lbng    = (const float*)d_in[21];
    const float* lbnb    = (const float*)d_in[22];
    const float* pred0_w = (const float*)d_in[23];
    const float* pred0_b = (const float*)d_in[24];
    const float* predh_w = (const float*)d_in[25];
    const float* predh_b = (const float*)d_in[26];
    float* out = (float*)d_out;

    uint8_t* wsb = (uint8_t*)d_ws;
    unsigned short* Z1      = (unsigned short*)(wsb + (16ull << 20));
    unsigned short* Z2      = (unsigned short*)(wsb + (48ull << 20));
    unsigned short* Z2a     = (unsigned short*)(wsb + (84ull << 20));
    unsigned short* Z2b     = (unsigned short*)(wsb + (88ull << 20));
    unsigned short* pooled3 = (unsigned short*)(wsb + (92ull << 20));
    unsigned short* Z3a     = (unsigned short*)(wsb + (92ull << 20) + 131072);
    unsigned short* Z3b     = (unsigned short*)(wsb + (92ull << 20) + 262144);
    unsigned short* Wt      = (unsigned short*)(wsb + (93ull << 20));
    float* zbase = (float*)(wsb + (94ull << 20));
    float* ts0   = zbase;                        // 32768 f32 (atomic -> zeroed)
    float* ts1   = zbase + 32768;                // 65536 f32 (exact stores)
    float* stats = zbase + 32768 + 65536;        // 6 x [NSLOT][512] f32
    auto SP = [&](int i) { return stats + i * (NSLOT * 512); };
    size_t zbytes = (32768 + 65536 + 6 * NSLOT * 512) * sizeof(float);

    hipMemsetAsync(zbase, 0, zbytes, stream);
    transpose_weights<<<352, 256, 0, stream>>>(l1_w1, l1_w2, lw1, lw2, Wt);

    // layer 1
    gemm1_fused<<<N1 / 128, 512, 0, stream>>>(x, Wt, l1_b1, Z1, SP(0), ts0);
    gemm1b_kernel<<<N1 / 128, 512, 0, stream>>>(
        Z1, SP(0), l1_bn1g, l1_bn1b, Wt + 32768, l1_b2, Z2, SP(1));

    // layer 2
    gemm2a_kernel<<<N2 / 32, 512, 0, stream>>>(
        Z2, SP(1), l1_bng, l1_bnb, Wt + 98304, lb1, Z2a, SP(2), ts1);
    gemm_bn32_kernel<<<N2 / 32, 512, 0, stream>>>(
        Z2a, SP(2), lbn1g, lbn1b, 1.f / N2, Wt + 163840, lb2, Z2b, SP(3));

    // layer 3 (8 blocks each; G3A pools 32 from Z2b and emits pooled3)
    gemm3a_kernel<<<NB / 32, 512, 0, stream>>>(
        Z2b, SP(3), lbng, lbnb, Wt + 229376, lb1 + 256, pooled3, Z3a, SP(4));
    gemm_bn32_kernel<<<NB / 32, 512, 0, stream>>>(
        Z3a, SP(4), lbn1g + 256, lbn1b + 256, 1.f / NB, Wt + 294912, lb2 + 256, Z3b, SP(5));

    // readout
    head_kernel<<<NB, 256, 0, stream>>>(ts0, ts1, pooled3, Z3b, SP(5),
                                        lbng + 256, lbnb + 256,
                                        pred0_w, pred0_b, predh_w, predh_b, out);
}